// Round 11
// baseline (246.047 us; speedup 1.0000x reference)
//
#include <hip/hip_runtime.h>
#include <hip/hip_cooperative_groups.h>
#include <cmath>

namespace cg = cooperative_groups;

#define D_MODEL 512
#define N_HEADS 8
#define HEAD_DIM 64
#define D_FF 2048
#define SEQ 2048
#define BATCH 2
#define MROWS (BATCH * SEQ) /* 4096 */

typedef __attribute__((ext_vector_type(8))) short short8;
typedef __attribute__((ext_vector_type(4))) float float4v;
typedef unsigned short ushort_t;

static __device__ __forceinline__ ushort_t f2bf(float f) {
    union { float f; unsigned u; } v; v.f = f;
    unsigned r = (v.u + 0x7FFFu + ((v.u >> 16) & 1u)) >> 16;
    return (ushort_t)r;
}
static __device__ __forceinline__ ushort_t f2bf_trunc(float f) {
    union { float f; unsigned u; } v; v.f = f;
    return (ushort_t)(v.u >> 16);
}

// async global->LDS, 16B per lane; LDS dest = wave-uniform base + lane*16
static __device__ __forceinline__ void gload16(const void* g, void* l) {
    __builtin_amdgcn_global_load_lds(
        (__attribute__((address_space(1))) void*)(unsigned long long)g,
        (__attribute__((address_space(3))) void*)(unsigned)(unsigned long long)l,
        16, 0, 0);
}

// ===========================================================================
// Device stage functions (used by the cooperative mega-kernel)
// ===========================================================================

// GEMM stage: BM=128, BN=64, BK=32 m97-style. MODE 1 = bf16+bias+ReLU,
// MODE 2 = fp32 raw split-K partial at (float*)Cv + zoff.
template <int MODE>
__device__ void gemm64_stage(
    const ushort_t* __restrict__ A, const ushort_t* __restrict__ BT,
    const float* __restrict__ bias, void* __restrict__ Cv,
    int N, int K, int m0, int n0, int kbase, int Klen, size_t zoff,
    ushort_t* __restrict__ sm)
{
    ushort_t* As = sm;          // 128*32 = 8 KB
    ushort_t* Bs = sm + 4096;   // 64*32 = 4 KB

    const int t = threadIdx.x;
    const int w = t >> 6, lane = t & 63, l16 = lane & 15, quad = lane >> 4;
    const int mbase = (w >> 1) * 64;
    const int nbase = (w & 1) * 32;
    const int srow = lane >> 2;
    const int schk = (lane & 3) * 8;

    float4v acc[4][2];
    #pragma unroll
    for (int mt = 0; mt < 4; ++mt)
        #pragma unroll
        for (int nt = 0; nt < 2; ++nt)
            acc[mt][nt] = (float4v){0.f, 0.f, 0.f, 0.f};

    for (int ks = kbase; ks < kbase + Klen; ks += 32) {
        __syncthreads();
        #pragma unroll
        for (int g = 0; g < 2; ++g)
            gload16(A + (size_t)(m0 + g * 64 + w * 16 + srow) * K + ks + schk,
                    &As[g * 2048 + w * 512]);
        gload16(BT + (size_t)(n0 + w * 16 + srow) * K + ks + schk, &Bs[w * 512]);
        __syncthreads();

        short8 af[4], bf8[2];
        #pragma unroll
        for (int mt = 0; mt < 4; ++mt)
            af[mt] = *(const short8*)&As[(mbase + mt * 16 + l16) * 32 + quad * 8];
        #pragma unroll
        for (int nt = 0; nt < 2; ++nt)
            bf8[nt] = *(const short8*)&Bs[(nbase + nt * 16 + l16) * 32 + quad * 8];
        #pragma unroll
        for (int mt = 0; mt < 4; ++mt)
            #pragma unroll
            for (int nt = 0; nt < 2; ++nt)
                acc[mt][nt] = __builtin_amdgcn_mfma_f32_16x16x32_bf16(
                    af[mt], bf8[nt], acc[mt][nt], 0, 0, 0);
    }

    #pragma unroll
    for (int mt = 0; mt < 4; ++mt) {
        #pragma unroll
        for (int nt = 0; nt < 2; ++nt) {
            int gcol = n0 + nbase + nt * 16 + l16;
            float b = (MODE == 2) ? 0.f : bias[gcol];
            #pragma unroll
            for (int r = 0; r < 4; ++r) {
                int grow = m0 + mbase + mt * 16 + quad * 4 + r;
                float v = acc[mt][nt][r] + b;
                if (MODE == 1) {
                    v = fmaxf(v, 0.f);
                    ((ushort_t*)Cv)[(size_t)grow * N + gcol] = f2bf(v);
                } else {
                    ((float*)Cv + zoff)[(size_t)grow * N + gcol] = v;
                }
            }
        }
    }
}

// QKV stage: BN=64 GEMM + head-layout epilogue (64 | 512, block-uniform sel).
__device__ void qkv64_stage(
    const ushort_t* __restrict__ A, const ushort_t* __restrict__ BT,
    const float* __restrict__ bq, const float* __restrict__ bk,
    const float* __restrict__ bv,
    ushort_t* __restrict__ Qb, ushort_t* __restrict__ Kb,
    ushort_t* __restrict__ VTb,
    int m0, int n0, ushort_t* __restrict__ sm)
{
    ushort_t* As = sm;
    ushort_t* Bs = sm + 4096;

    const int t = threadIdx.x;
    const int w = t >> 6, lane = t & 63, l16 = lane & 15, quad = lane >> 4;
    const int mbase = (w >> 1) * 64;
    const int nbase = (w & 1) * 32;
    const int srow = lane >> 2;
    const int schk = (lane & 3) * 8;
    const int K = 512;

    float4v acc[4][2];
    #pragma unroll
    for (int mt = 0; mt < 4; ++mt)
        #pragma unroll
        for (int nt = 0; nt < 2; ++nt)
            acc[mt][nt] = (float4v){0.f, 0.f, 0.f, 0.f};

    for (int ks = 0; ks < 512; ks += 32) {
        __syncthreads();
        #pragma unroll
        for (int g = 0; g < 2; ++g)
            gload16(A + (size_t)(m0 + g * 64 + w * 16 + srow) * K + ks + schk,
                    &As[g * 2048 + w * 512]);
        gload16(BT + (size_t)(n0 + w * 16 + srow) * K + ks + schk, &Bs[w * 512]);
        __syncthreads();

        short8 af[4], bf8[2];
        #pragma unroll
        for (int mt = 0; mt < 4; ++mt)
            af[mt] = *(const short8*)&As[(mbase + mt * 16 + l16) * 32 + quad * 8];
        #pragma unroll
        for (int nt = 0; nt < 2; ++nt)
            bf8[nt] = *(const short8*)&Bs[(nbase + nt * 16 + l16) * 32 + quad * 8];
        #pragma unroll
        for (int mt = 0; mt < 4; ++mt)
            #pragma unroll
            for (int nt = 0; nt < 2; ++nt)
                acc[mt][nt] = __builtin_amdgcn_mfma_f32_16x16x32_bf16(
                    af[mt], bf8[nt], acc[mt][nt], 0, 0, 0);
    }

    const int tsel = n0 >> 9;
    const float* bias = (tsel == 0) ? bq : (tsel == 1) ? bk : bv;
    const float scl = (tsel == 0) ? 0.18033688f : 1.0f;  // 0.125 * log2(e)
    ushort_t* dst = (tsel == 0) ? Qb : Kb;

    #pragma unroll
    for (int mt = 0; mt < 4; ++mt) {
        #pragma unroll
        for (int nt = 0; nt < 2; ++nt) {
            int gcol = n0 + nbase + nt * 16 + l16;
            int lcol = gcol - (tsel << 9);
            int h = lcol >> 6, dh = lcol & 63;
            float b = bias[lcol];
            #pragma unroll
            for (int r = 0; r < 4; ++r) {
                int grow = m0 + mbase + mt * 16 + quad * 4 + r;
                int bb = grow >> 11, s = grow & 2047;
                float v = (acc[mt][nt][r] + b) * scl;
                if (tsel < 2)
                    dst[(((size_t)(bb * N_HEADS + h)) * SEQ + s) * HEAD_DIM + dh] = f2bf(v);
                else
                    VTb[(((size_t)(bb * N_HEADS + h)) * HEAD_DIM + dh) * SEQ + s] = f2bf(v);
            }
        }
    }
}

// Attention stage (r8 v4): async dbuf K/V via global_load_lds (XOR-swizzled),
// raw s_barrier, vmcnt(4) pipelining, fixed-max exp2 softmax, split-K x2.
__device__ void attn_stage(
    const ushort_t* __restrict__ Qg, const ushort_t* __restrict__ Kg,
    const ushort_t* __restrict__ VTg,
    float* __restrict__ Opart, float* __restrict__ Lpart,
    int bh, int q0, int ks, ushort_t* __restrict__ sm)
{
    ushort_t* Kbp[2] = { sm, sm + 4096 };
    ushort_t* Vbp[2] = { sm + 8192, sm + 12288 };
    const int t = threadIdx.x;
    const int w = t >> 6;
    ushort_t* Psw = sm + 16384 + w * 1024;

    const int lane = t & 63;
    const int l16 = lane & 15;
    const int quad = lane >> 4;
    const int qbase = q0 + w * 16;
    const float M2 = 14.4269504f;

    const int r0 = t >> 3;
    const int r1 = r0 + 32;
    const int g0 = (t & 7) ^ (r0 & 7);
    const int g1 = (t & 7) ^ (r1 & 7);
    const size_t kgrow = (size_t)bh * SEQ;
    const size_t vgrow = (size_t)bh * HEAD_DIM;

#define ATTN_ST(b, kb)                                                                     \
    {                                                                                      \
        gload16(Kg + (kgrow + (kb) + r0) * HEAD_DIM + g0 * 8, Kbp[b] + w * 512);           \
        gload16(Kg + (kgrow + (kb) + r1) * HEAD_DIM + g1 * 8, Kbp[b] + 2048 + w * 512);    \
        gload16(VTg + (vgrow + r0) * SEQ + (kb) + g0 * 8, Vbp[b] + w * 512);               \
        gload16(VTg + (vgrow + r1) * SEQ + (kb) + g1 * 8, Vbp[b] + 2048 + w * 512);        \
    }

    short8 aq[2];
    {
        const ushort_t* qp = Qg + ((size_t)bh * SEQ + qbase + l16) * HEAD_DIM + quad * 8;
        aq[0] = *(const short8*)(qp);
        aq[1] = *(const short8*)(qp + 32);
    }

    float4v o[4] = {};
    float l_acc[4] = {0.f, 0.f, 0.f, 0.f};

    ATTN_ST(0, ks * 1024)

    for (int kt = 0; kt < 16; ++kt) {
        const int cur = kt & 1;
        if (kt < 15) {
            ATTN_ST(cur ^ 1, ks * 1024 + (kt + 1) * 64)
            asm volatile("s_waitcnt vmcnt(4)" ::: "memory");
        } else {
            asm volatile("s_waitcnt vmcnt(0)" ::: "memory");
        }
        asm volatile("s_barrier" ::: "memory");

        const ushort_t* Kc = Kbp[cur];
        const ushort_t* Vc = Vbp[cur];

        float4v s[4];
        #pragma unroll
        for (int nt = 0; nt < 4; ++nt) s[nt] = (float4v){0.f, 0.f, 0.f, 0.f};
        #pragma unroll
        for (int c = 0; c < 2; ++c) {
            const int poff = (((c * 4 + quad) ^ (l16 & 7)) << 3);
            #pragma unroll
            for (int nt = 0; nt < 4; ++nt) {
                short8 bk8 = *(const short8*)&Kc[(nt * 16 + l16) * 64 + poff];
                s[nt] = __builtin_amdgcn_mfma_f32_16x16x32_bf16(aq[c], bk8, s[nt], 0, 0, 0);
            }
        }

        #pragma unroll
        for (int nt = 0; nt < 4; ++nt) {
            #pragma unroll
            for (int r = 0; r < 4; ++r) {
                float p = exp2f(s[nt][r] - M2);
                s[nt][r] = p;
                l_acc[r] += p;
            }
        }

        #pragma unroll
        for (int nt = 0; nt < 4; ++nt)
            #pragma unroll
            for (int r = 0; r < 4; ++r) {
                int row = quad * 4 + r;
                int key = nt * 16 + l16;
                Psw[row * 64 + (((key >> 3) ^ (row & 7)) << 3) + (key & 7)] =
                    f2bf_trunc(s[nt][r]);
            }
        asm volatile("s_waitcnt lgkmcnt(0)" ::: "memory");

        #pragma unroll
        for (int c = 0; c < 2; ++c) {
            short8 ap = *(const short8*)&Psw[l16 * 64 + ((((c << 2) + quad) ^ (l16 & 7)) << 3)];
            const int poff = (((c * 4 + quad) ^ (l16 & 7)) << 3);
            #pragma unroll
            for (int dt = 0; dt < 4; ++dt) {
                short8 bv8 = *(const short8*)&Vc[(dt * 16 + l16) * 64 + poff];
                o[dt] = __builtin_amdgcn_mfma_f32_16x16x32_bf16(ap, bv8, o[dt], 0, 0, 0);
            }
        }

        asm volatile("s_barrier" ::: "memory");
    }
#undef ATTN_ST

    const size_t pbase = ((size_t)(ks * 16 + bh)) * SEQ;
    #pragma unroll
    for (int r = 0; r < 4; ++r) {
        float L = l_acc[r];
        #pragma unroll
        for (int msk = 1; msk < 16; msk <<= 1) L += __shfl_xor(L, msk);
        int qrow = qbase + quad * 4 + r;
        if (l16 == 0) Lpart[pbase + qrow] = L;
        #pragma unroll
        for (int dt = 0; dt < 4; ++dt)
            Opart[(pbase + qrow) * HEAD_DIM + dt * 16 + l16] = o[dt][r];
    }
}

// Residual + LayerNorm stage (grid-stride).
template <int WRITE_BF>
__device__ void ln_stage(
    const float* __restrict__ X, const float* __restrict__ P0,
    const float* __restrict__ P1, const float* __restrict__ bias,
    const float* __restrict__ gam, const float* __restrict__ bet,
    float* __restrict__ O, ushort_t* __restrict__ Ob, ushort_t* __restrict__ sm)
{
    float* sb = (float*)sm;
    float* ssb = sb + 4;
    const int t = threadIdx.x;
    for (int row = blockIdx.x; row < MROWS; row += gridDim.x) {
        const size_t ro = (size_t)row * D_MODEL;
        float v0 = X[ro + t]       + P0[ro + t]       + P1[ro + t]       + bias[t];
        float v1 = X[ro + t + 256] + P0[ro + t + 256] + P1[ro + t + 256] + bias[t + 256];
        float s = v0 + v1;
        float ss = v0 * v0 + v1 * v1;
        #pragma unroll
        for (int off = 32; off > 0; off >>= 1) {
            s  += __shfl_down(s, off);
            ss += __shfl_down(ss, off);
        }
        if ((t & 63) == 0) { sb[t >> 6] = s; ssb[t >> 6] = ss; }
        __syncthreads();
        float S  = sb[0] + sb[1] + sb[2] + sb[3];
        float SS = ssb[0] + ssb[1] + ssb[2] + ssb[3];
        float mu  = S * (1.0f / D_MODEL);
        float var = SS * (1.0f / D_MODEL) - mu * mu;
        float inv = rsqrtf(var + 1e-5f);
        float o0 = (v0 - mu) * inv * gam[t] + bet[t];
        float o1 = (v1 - mu) * inv * gam[t + 256] + bet[t + 256];
        O[ro + t]       = o0;
        O[ro + t + 256] = o1;
        if (WRITE_BF) {
            Ob[ro + t]       = f2bf(o0);
            Ob[ro + t + 256] = f2bf(o1);
        }
        __syncthreads();
    }
}

// ---------------------------------------------------------------------------
// Cooperative mega-kernel: 9 stages, 8 grid syncs. All stages grid-stride
// (any grid size works; intended 768 or 1024 blocks x 256).
// ---------------------------------------------------------------------------
__global__ __launch_bounds__(256, 4) void mega_k(
    const float* x,
    const float* Wq, const float* bq, const float* Wk, const float* bk,
    const float* Wv, const float* bv, const float* Wo, const float* bo,
    const float* W1, const float* b1, const float* W2, const float* b2,
    const float* g1, const float* be1, const float* g2, const float* be2,
    float* out, float* ws)
{
    cg::grid_group grid = cg::this_grid();
    __shared__ __align__(16) ushort_t sm[20480];   // 40960 B

    ushort_t* WoT   = (ushort_t*)(ws);
    ushort_t* W1T   = (ushort_t*)(ws + 131072);
    ushort_t* W2T   = (ushort_t*)(ws + 655360);
    ushort_t* WqkvT = (ushort_t*)(ws + 1179648);
    ushort_t* xb    = (ushort_t*)(ws + 1572864);
    ushort_t* Qb    = (ushort_t*)(ws + 2621440);
    ushort_t* Kb    = (ushort_t*)(ws + 3670016);
    ushort_t* VTb   = (ushort_t*)(ws + 4718592);
    ushort_t* Ctx   = (ushort_t*)(ws + 5767168);
    float*    Lpart = ws + 6815744;
    float*    Hh    = ws + 6881280;
    float*    P0    = ws + 8978432;
    float*    P1    = ws + 11075584;
    float*    Opart = ws + 8978432;                // P0/P1 slot (dead before Wo)
    ushort_t* FF1   = (ushort_t*)(ws + 1572864);   // xb..VTb slot (dead by W1)
    ushort_t* Hhb   = (ushort_t*)(ws + 5767168);   // Ctx slot (dead after Wo)

    const int bid = blockIdx.x;
    const int G = gridDim.x;
    const int t = threadIdx.x;

    // stage 0: prep
    for (int tile = bid; tile < 5120; tile += G) {
        if (tile >= 3072) {
            int i = (tile - 3072) * 256 + t;
            float4 f = ((const float4*)x)[i];
            ushort4 o;
            o.x = f2bf(f.x); o.y = f2bf(f.y); o.z = f2bf(f.z); o.w = f2bf(f.w);
            ((ushort4*)xb)[i] = o;
        } else {
            const float* src; ushort_t* dst; int Kd, Nd, tloc;
            if (tile < 1024) {
                int wsel = tile >> 8; tloc = tile & 255; Kd = 512; Nd = 512;
                if (wsel == 0)      { src = Wq; dst = WqkvT; }
                else if (wsel == 1) { src = Wk; dst = WqkvT + (size_t)512 * 512; }
                else if (wsel == 2) { src = Wv; dst = WqkvT + (size_t)1024 * 512; }
                else                { src = Wo; dst = WoT; }
            } else if (tile < 2048) { tloc = tile - 1024; Kd = 512;  Nd = 2048; src = W1; dst = W1T; }
            else                    { tloc = tile - 2048; Kd = 2048; Nd = 512;  src = W2; dst = W2T; }
            int tn = Nd >> 5;
            int k0 = (tloc / tn) << 5, n0 = (tloc % tn) << 5;
            float* tl = (float*)sm;
            int c = t & 31, r = t >> 5;
            #pragma unroll
            for (int i = 0; i < 4; ++i)
                tl[(r + i * 8) * 33 + c] = src[(size_t)(k0 + r + i * 8) * Nd + n0 + c];
            __syncthreads();
            #pragma unroll
            for (int i = 0; i < 4; ++i)
                dst[(size_t)(n0 + r + i * 8) * Kd + k0 + c] = f2bf(tl[c * 33 + r + i * 8]);
            __syncthreads();
        }
    }
    grid.sync();

    // stage 1: QKV (768 units)
    for (int u = bid; u < 768; u += G)
        qkv64_stage(xb, WqkvT, bq, bk, bv, Qb, Kb, VTb, (u / 24) * 128, (u % 24) * 64, sm);
    grid.sync();

    // stage 2: attention (1024 units)
    for (int u = bid; u < 1024; u += G)
        attn_stage(Qb, Kb, VTb, Opart, Lpart, u & 15, ((u >> 4) & 31) * 64, u >> 9, sm);
    grid.sync();

    // stage 3: combine (2048 units)
    for (int u = bid; u < 2048; u += G) {
        int gidx = u * 256 + t;
        int d4 = gidx & 15;
        int q  = (gidx >> 4) & 2047;
        int bh = gidx >> 15;
        float ax = 0.f, ay = 0.f, az = 0.f, aw = 0.f, L = 0.f;
        #pragma unroll
        for (int ks = 0; ks < 2; ++ks) {
            size_t row = ((size_t)(ks * 16 + bh) * SEQ + q) * HEAD_DIM;
            float4 a = ((const float4*)(Opart + row))[d4];
            ax += a.x; ay += a.y; az += a.z; aw += a.w;
            L += Lpart[ks * 16 * SEQ + bh * SEQ + q];
        }
        float inv = 1.0f / L;
        ushort4 o4;
        o4.x = f2bf(ax * inv);
        o4.y = f2bf(ay * inv);
        o4.z = f2bf(az * inv);
        o4.w = f2bf(aw * inv);
        int bb = bh >> 3, hh = bh & 7;
        *(ushort4*)&Ctx[((size_t)(bb * SEQ + q)) * D_MODEL + hh * HEAD_DIM + d4 * 4] = o4;
    }
    grid.sync();

    // stage 4: Wo split-K x2 (512 units)
    for (int u = bid; u < 512; u += G) {
        int n0 = (u & 7) * 64, m0 = ((u >> 3) & 31) * 128, z = u >> 8;
        gemm64_stage<2>(Ctx, WoT, nullptr, P0, 512, 512, m0, n0, z * 256, 256,
                        (size_t)z * 2097152, sm);
    }
    grid.sync();

    // stage 5: LN1
    ln_stage<1>(x, P0, P1, bo, g1, be1, Hh, Hhb, sm);
    grid.sync();

    // stage 6: W1 + ReLU (1024 units)
    for (int u = bid; u < 1024; u += G)
        gemm64_stage<1>(Hhb, W1T, b1, FF1, 2048, 512, (u >> 5) * 128, (u & 31) * 64,
                        0, 512, 0, sm);
    grid.sync();

    // stage 7: W2 split-K x2 (512 units)
    for (int u = bid; u < 512; u += G) {
        int n0 = (u & 7) * 64, m0 = ((u >> 3) & 31) * 128, z = u >> 8;
        gemm64_stage<2>(FF1, W2T, nullptr, P0, 512, 2048, m0, n0, z * 1024, 1024,
                        (size_t)z * 2097152, sm);
    }
    grid.sync();

    // stage 8: LN2
    ln_stage<0>(Hh, P0, P1, b2, g2, be2, out, (ushort_t*)nullptr, sm);
}

// ===========================================================================
// Fallback kernels — round-9 set, verbatim (known-good, 229 us)
// ===========================================================================

__global__ __launch_bounds__(256) void prep_k(
    const float* __restrict__ x,
    const float* __restrict__ Wq, const float* __restrict__ Wk,
    const float* __restrict__ Wv, const float* __restrict__ Wo,
    const float* __restrict__ W1, const float* __restrict__ W2,
    ushort_t* __restrict__ xb,
    ushort_t* __restrict__ WqkvT, ushort_t* __restrict__ WoT,
    ushort_t* __restrict__ W1T, ushort_t* __restrict__ W2T)
{
    int tile = blockIdx.x;
    if (tile >= 3072) {
        int i = (tile - 3072) * 256 + threadIdx.x;
        float4 f = ((const float4*)x)[i];
        ushort4 o;
        o.x = f2bf(f.x); o.y = f2bf(f.y); o.z = f2bf(f.z); o.w = f2bf(f.w);
        ((ushort4*)xb)[i] = o;
        return;
    }
    const float* src; ushort_t* dst; int Kd, Nd, tloc;
    if (tile < 1024) {
        int wsel = tile >> 8; tloc = tile & 255; Kd = 512; Nd = 512;
        if (wsel == 0)      { src = Wq; dst = WqkvT; }
        else if (wsel == 1) { src = Wk; dst = WqkvT + (size_t)512 * 512; }
        else if (wsel == 2) { src = Wv; dst = WqkvT + (size_t)1024 * 512; }
        else                { src = Wo; dst = WoT; }
    } else if (tile < 2048) { tloc = tile - 1024; Kd = 512;  Nd = 2048; src = W1; dst = W1T; }
    else                    { tloc = tile - 2048; Kd = 2048; Nd = 512;  src = W2; dst = W2T; }
    int tn = Nd >> 5;
    int k0 = (tloc / tn) << 5, n0 = (tloc % tn) << 5;
    __shared__ float tl[32][33];
    int c = threadIdx.x & 31, r = threadIdx.x >> 5;
    #pragma unroll
    for (int i = 0; i < 4; ++i)
        tl[r + i * 8][c] = src[(size_t)(k0 + r + i * 8) * Nd + n0 + c];
    __syncthreads();
    #pragma unroll
    for (int i = 0; i < 4; ++i)
        dst[(size_t)(n0 + r + i * 8) * Kd + k0 + c] = f2bf(tl[c][r + i * 8]);
}

template <int BN, int NT, int MODE>
__global__ __launch_bounds__(256) void gemm_std_k(
    const ushort_t* __restrict__ A, const ushort_t* __restrict__ BT,
    const float* __restrict__ bias, void* __restrict__ Cv,
    int N, int K, int Klen, size_t zstride)
{
    __shared__ ushort_t As[128 * 32];
    __shared__ ushort_t Bs[BN * 32];

    const int t = threadIdx.x;
    const int w = t >> 6, lane = t & 63, l16 = lane & 15, quad = lane >> 4;
    const int m0 = blockIdx.y * 128;
    const int n0 = blockIdx.x * BN;
    const int kbase = blockIdx.z * Klen;
    const int mbase = (w >> 1) * 64;
    const int nbase = (w & 1) * (NT * 16);
    const int srow = lane >> 2;
    const int schk = (lane & 3) * 8;

    float4v acc[4][NT];
    #pragma unroll
    for (int mt = 0; mt < 4; ++mt)
        #pragma unroll
        for (int nt = 0; nt < NT; ++nt)
            acc[mt][nt] = (float4v){0.f, 0.f, 0.f, 0.f};

    for (int ks = kbase; ks < kbase + Klen; ks += 32) {
        __syncthreads();
        #pragma unroll
        for (int g = 0; g < 2; ++g)
            gload16(A + (size_t)(m0 + g * 64 + w * 16 + srow) * K + ks + schk,
                    &As[g * 2048 + w * 512]);
        #pragma unroll
        for (int g = 0; g < BN / 64; ++g)
            gload16(BT + (size_t)(n0 + g * 64 + w * 16 + srow) * K + ks + schk,
                    &Bs[g * 2048 + w * 512]);
        __syncthreads();

        short8 af[4], bf8[NT];
        #pragma unroll
        for (int mt = 0; mt < 4; ++mt)
            af[mt] = *(const short8*)&As[(mbase + mt * 16 + l16) * 32 + quad * 8];
        #pragma unroll
        for (int nt = 0; nt < NT; ++nt)
            bf8[nt] = *(const short8*)&Bs[(nbase + nt * 16 + l16) * 32 + quad * 8];
        #pragma unroll
        for (int mt = 0; mt < 4; ++mt)
            #pragma unroll
            for (int nt = 0; nt < NT; ++nt)
                acc[mt][nt] = __builtin_amdgcn_mfma_f32_16x16x32_bf16(
                    af[mt], bf8[nt], acc[mt][nt], 0, 0, 0);
    }

    float* Cf = (float*)Cv + blockIdx.z * zstride;
    #pragma unroll
    for (int mt = 0; mt < 4; ++mt) {
        #pragma unroll
        for (int nt = 0; nt < NT; ++nt) {
            int gcol = n0 + nbase + nt * 16 + l16;
            float b = (MODE == 2) ? 0.f : bias[gcol];
            #pragma unroll
            for (int r = 0; r < 4; ++r) {
                int grow = m0 + mbase + mt * 16 + quad * 4 + r;
                float v = acc[mt][nt][r] + b;
                if (MODE == 1) v = fmaxf(v, 0.f);
                if (MODE == 1) ((ushort_t*)Cv)[(size_t)grow * N + gcol] = f2bf(v);
                else           Cf[(size_t)grow * N + gcol] = v;
            }
        }
    }
}

__global__ __launch_bounds__(256) void gemm_qkv_k(
    const ushort_t* __restrict__ A, const ushort_t* __restrict__ BT,
    const float* __restrict__ bq, const float* __restrict__ bk,
    const float* __restrict__ bv,
    ushort_t* __restrict__ Qb, ushort_t* __restrict__ Kb,
    ushort_t* __restrict__ VTb)
{
    __shared__ ushort_t As[128 * 32];
    __shared__ ushort_t Bs[128 * 32];

    const int t = threadIdx.x;
    const int w = t >> 6, lane = t & 63, l16 = lane & 15, quad = lane >> 4;
    const int m0 = blockIdx.y * 128;
    const int n0 = blockIdx.x * 128;
    const int mbase = (w >> 1) * 64;
    const int nbase = (w & 1) * 64;
    const int srow = lane >> 2;
    const int schk = (lane & 3) * 8;
    const int K = 512;

    float4v acc[4][4];
    #pragma unroll
    for (int mt = 0; mt < 4; ++mt)
        #pragma unroll
        for (int nt = 0; nt < 4; ++nt)
            acc[mt][nt] = (float4v){0.f, 0.f, 0.f, 0.f};

    for (int ks = 0; ks < 512; ks += 32) {
        __syncthreads();
        #pragma unroll
        for (int g = 0; g < 2; ++g)
            gload16(A + (size_t)(m0 + g * 64 + w * 16 + srow) * K + ks + schk,
                    &As[g * 2048 + w * 512]);
        #pragma unroll
        for (int g = 0; g < 2; ++g)
            gload16(BT + (size_t)(n0 + g * 64 + w * 16 + srow) * K + ks + schk,
                    &Bs[g * 2048 + w * 512]);
        __syncthreads();

        short8 af[4], bf8[4];
        #pragma unroll
        for (int mt = 0; mt < 4; ++mt)
            af[mt] = *(const short8*)&As[(mbase + mt * 16 + l16) * 32 + quad * 8];
        #pragma unroll
        for (int nt = 0; nt < 4; ++nt)
            bf8[nt] = *(const short8*)&Bs[(nbase + nt * 16 + l16) * 32 + quad * 8];
        #pragma unroll
        for (int mt = 0; mt < 4; ++mt)
            #pragma unroll
            for (int nt = 0; nt < 4; ++nt)
                acc[mt][nt] = __builtin_amdgcn_mfma_f32_16x16x32_bf16(
                    af[mt], bf8[nt], acc[mt][nt], 0, 0, 0);
    }

    const int tsel = n0 >> 9;
    const float* bias = (tsel == 0) ? bq : (tsel == 1) ? bk : bv;
    const float scl = (tsel == 0) ? 0.18033688f : 1.0f;
    ushort_t* dst = (tsel == 0) ? Qb : Kb;

    #pragma unroll
    for (int mt = 0; mt < 4; ++mt) {
        #pragma unroll
        for (int nt = 0; nt < 4; ++nt) {
            int gcol = n0 + nbase + nt * 16 + l16;
            int lcol = gcol - (tsel << 9);
            int h = lcol >> 6, dh = lcol & 63;
            float b = bias[lcol];
            #pragma unroll
            for (int r = 0; r < 4; ++r) {
                int grow = m0 + mbase + mt * 16 + quad * 4 + r;
                int bb = grow >> 11, s = grow & 2047;
                float v = (acc[mt][nt][r] + b) * scl;
                if (tsel < 2)
                    dst[(((size_t)(bb * N_HEADS + h)) * SEQ + s) * HEAD_DIM + dh] = f2bf(v);
                else
                    VTb[(((size_t)(bb * N_HEADS + h)) * HEAD_DIM + dh) * SEQ + s] = f2bf(v);
            }
        }
    }
}

__global__ __launch_bounds__(256) void attn_mfma_k(
    const ushort_t* __restrict__ Qg, const ushort_t* __restrict__ Kg,
    const ushort_t* __restrict__ VTg,
    float* __restrict__ Opart, float* __restrict__ Lpart)
{
    __shared__ __align__(16) ushort_t smem[20480];
    attn_stage(Qg, Kg, VTg, Opart, Lpart,
               blockIdx.x, blockIdx.y * 64, blockIdx.z, smem);
}

__global__ __launch_bounds__(256) void attn_comb_k(
    const float* __restrict__ Op, const float* __restrict__ Lp,
    ushort_t* __restrict__ ctx)
{
    int g = blockIdx.x * 256 + threadIdx.x;
    int d4 = g & 15;
    int q  = (g >> 4) & 2047;
    int bh = g >> 15;
    float ax = 0.f, ay = 0.f, az = 0.f, aw = 0.f, L = 0.f;
    #pragma unroll
    for (int ks = 0; ks < 2; ++ks) {
        size_t row = ((size_t)(ks * 16 + bh) * SEQ + q) * HEAD_DIM;
        float4 a = ((const float4*)(Op + row))[d4];
        ax += a.x; ay += a.y; az += a.z; aw += a.w;
        L += Lp[ks * 16 * SEQ + bh * SEQ + q];
    }
    float inv = 1.0f / L;
    ushort4 o4;
    o4.x = f2bf(ax * inv);
    o4.y = f2bf(ay * inv);
    o4.z = f2bf(az * inv);
    o4.w = f2bf(aw * inv);
    int bb = bh >> 3, hh = bh & 7;
    *(ushort4*)&ctx[((size_t)(bb * SEQ + q)) * D_MODEL + hh * HEAD_DIM + d4 * 4] = o4;
}

template <int WRITE_BF>
__global__ __launch_bounds__(256) void add_ln_k(
    const float* __restrict__ X, const float* __restrict__ P0,
    const float* __restrict__ P1, const float* __restrict__ bias,
    const float* __restrict__ gam, const float* __restrict__ bet,
    float* __restrict__ O, ushort_t* __restrict__ Ob)
{
    const int row = blockIdx.x;
    const int t = threadIdx.x;
    const size_t ro = (size_t)row * D_MODEL;

    float v0 = X[ro + t]       + P0[ro + t]       + P1[ro + t]       + bias[t];
    float v1 = X[ro + t + 256] + P0[ro + t + 256] + P1[ro + t + 256] + bias[t + 256];
    float s = v0 + v1;
    float ss = v0 * v0 + v1 * v1;
    #pragma unroll
    for (int off = 32; off > 0; off >>= 1) {
        s  += __shfl_down(s, off);
        ss += __shfl_down(ss, off);
    }
    __shared__ float sb[4], ssb[4];
    if ((t & 63) == 0) { sb[t >> 6] = s; ssb[t >> 6] = ss; }
    __syncthreads();
    float S  = sb[0] + sb[1] + sb[2] + sb[3];
    float SS = ssb[0] + ssb[1] + ssb[2] + ssb[3];
    float mu  = S * (1.0f / D_MODEL);
    float var = SS * (1.0f / D_MODEL) - mu * mu;
    float inv = rsqrtf(var + 1e-5f);
    float o0 = (v0 - mu) * inv * gam[t] + bet[t];
    float o1 = (v1 - mu) * inv * gam[t + 256] + bet[t + 256];
    O[ro + t]       = o0;
    O[ro + t + 256] = o1;
    if (WRITE_BF) {
        Ob[ro + t]       = f2bf(o0);
        Ob[ro + t + 256] = f2bf(o1);
    }
}

// ---------------------------------------------------------------------------
extern "C" void kernel_launch(void* const* d_in, const int* in_sizes, int n_in,
                              void* d_out, int out_size, void* d_ws, size_t ws_size,
                              hipStream_t stream)
{
    const float* x   = (const float*)d_in[0];
    const float* Wq  = (const float*)d_in[1];
    const float* bq  = (const float*)d_in[2];
    const float* Wk  = (const float*)d_in[3];
    const float* bk  = (const float*)d_in[4];
    const float* Wv  = (const float*)d_in[5];
    const float* bv  = (const float*)d_in[6];
    const float* Wo  = (const float*)d_in[7];
    const float* bo  = (const float*)d_in[8];
    const float* W1  = (const float*)d_in[9];
    const float* b1  = (const float*)d_in[10];
    const float* W2  = (const float*)d_in[11];
    const float* b2  = (const float*)d_in[12];
    const float* g1  = (const float*)d_in[13];
    const float* be1 = (const float*)d_in[14];
    const float* g2  = (const float*)d_in[15];
    const float* be2 = (const float*)d_in[16];
    float* out = (float*)d_out;
    float* ws  = (float*)d_ws;

    // ---- try cooperative mega-kernel (deterministic per-device decision) ----
    bool done = false;
    int dev = 0, coopAttr = 0, occ = 0;
    (void)hipGetDevice(&dev);
    (void)hipDeviceGetAttribute(&coopAttr, hipDeviceAttributeCooperativeLaunch, dev);
    hipError_t eo = hipOccupancyMaxActiveBlocksPerMultiprocessor(&occ, mega_k, 256, 0);
    if (coopAttr && eo == hipSuccess && occ >= 3) {
        int G = (occ >= 4) ? 1024 : 768;
        void* args[] = {
            (void*)&x,
            (void*)&Wq, (void*)&bq, (void*)&Wk, (void*)&bk,
            (void*)&Wv, (void*)&bv, (void*)&Wo, (void*)&bo,
            (void*)&W1, (void*)&b1, (void*)&W2, (void*)&b2,
            (void*)&g1, (void*)&be1, (void*)&g2, (void*)&be2,
            (void*)&out, (void*)&ws
        };
        if (hipLaunchCooperativeKernel((const void*)mega_k, dim3(G), dim3(256),
                                       args, 0, stream) == hipSuccess)
            done = true;
    }
    if (done) return;

    // ---- fallback: round-9 multi-kernel pipeline (known-good) ----
    ushort_t* WoT   = (ushort_t*)(ws);
    ushort_t* W1T   = (ushort_t*)(ws + 131072);
    ushort_t* W2T   = (ushort_t*)(ws + 655360);
    ushort_t* WqkvT = (ushort_t*)(ws + 1179648);
    ushort_t* xb    = (ushort_t*)(ws + 1572864);
    ushort_t* Qb    = (ushort_t*)(ws + 2621440);
    ushort_t* VTb   = (ushort_t*)(ws + 4718592);
    ushort_t* Kb    = (ushort_t*)(ws + 3670016);
    ushort_t* Ctx   = (ushort_t*)(ws + 5767168);
    float*    Lpart = ws + 6815744;
    float*    Hh    = ws + 6881280;
    float*    P0    = ws + 8978432;
    float*    P1    = ws + 11075584;
    float*    Opart = ws + 8978432;
    ushort_t* FF1   = (ushort_t*)(ws + 1572864);
    ushort_t* Hhb   = (ushort_t*)(ws + 5767168);

    prep_k<<<5120, 256, 0, stream>>>(x, Wq, Wk, Wv, Wo, W1, W2, xb, WqkvT, WoT, W1T, W2T);
    gemm_qkv_k<<<dim3(12, 32), 256, 0, stream>>>(xb, WqkvT, bq, bk, bv, Qb, Kb, VTb);
    attn_mfma_k<<<dim3(16, 32, 2), 256, 0, stream>>>(Qb, Kb, VTb, Opart, Lpart);
    attn_comb_k<<<2048, 256, 0, stream>>>(Opart, Lpart, Ctx);
    gemm_std_k<64, 2, 2><<<dim3(8, 32, 2), 256, 0, stream>>>(
        Ctx, WoT, nullptr, P0, 512, 512, 256, (size_t)MROWS * D_MODEL);
    add_ln_k<1><<<4096, 256, 0, stream>>>(x, P0, P1, bo, g1, be1, Hh, Hhb);
    gemm_std_k<128, 4, 1><<<dim3(16, 32), 256, 0, stream>>>(
        Hhb, W1T, b1, FF1, 2048, 512, 512, 0);
    gemm_std_k<64, 2, 2><<<dim3(8, 32, 2), 256, 0, stream>>>(
        FF1, W2T, nullptr, P0, 512, 2048, 1024, (size_t)MROWS * D_MODEL);
    add_ln_k<0><<<4096, 256, 0, stream>>>(Hh, P0, P1, b2, g2, be2, out, (ushort_t*)nullptr);
}

// Round 12
// 222.994 us; speedup vs baseline: 1.1034x; 1.1034x over previous
//
#include <hip/hip_runtime.h>
#include <cmath>

#define D_MODEL 512
#define N_HEADS 8
#define HEAD_DIM 64
#define D_FF 2048
#define SEQ 2048
#define BATCH 2
#define MROWS (BATCH * SEQ) /* 4096 */

typedef __attribute__((ext_vector_type(8))) short short8;
typedef __attribute__((ext_vector_type(4))) float float4v;
typedef unsigned short ushort_t;

static __device__ __forceinline__ ushort_t f2bf(float f) {
    union { float f; unsigned u; } v; v.f = f;
    unsigned r = (v.u + 0x7FFFu + ((v.u >> 16) & 1u)) >> 16;
    return (ushort_t)r;
}
static __device__ __forceinline__ ushort_t f2bf_trunc(float f) {
    union { float f; unsigned u; } v; v.f = f;
    return (ushort_t)(v.u >> 16);
}

// async global->LDS, 16B per lane; LDS dest = wave-uniform base + lane*16
static __device__ __forceinline__ void gload16(const void* g, void* l) {
    __builtin_amdgcn_global_load_lds(
        (__attribute__((address_space(1))) void*)(unsigned long long)g,
        (__attribute__((address_space(3))) void*)(unsigned)(unsigned long long)l,
        16, 0, 0);
}

// ---------------------------------------------------------------------------
// prep: weight transpose/convert (tiles 0..3071) + x fp32->bf16 (3072..5119)
// ---------------------------------------------------------------------------
__global__ __launch_bounds__(256) void prep_k(
    const float* __restrict__ x,
    const float* __restrict__ Wq, const float* __restrict__ Wk,
    const float* __restrict__ Wv, const float* __restrict__ Wo,
    const float* __restrict__ W1, const float* __restrict__ W2,
    ushort_t* __restrict__ xb,
    ushort_t* __restrict__ WqkvT, ushort_t* __restrict__ WoT,
    ushort_t* __restrict__ W1T, ushort_t* __restrict__ W2T)
{
    int tile = blockIdx.x;
    if (tile >= 3072) {                    // x -> bf16
        int i = (tile - 3072) * 256 + threadIdx.x;
        float4 f = ((const float4*)x)[i];
        ushort4 o;
        o.x = f2bf(f.x); o.y = f2bf(f.y); o.z = f2bf(f.z); o.w = f2bf(f.w);
        ((ushort4*)xb)[i] = o;
        return;
    }
    const float* src; ushort_t* dst; int Kd, Nd, tloc;
    if (tile < 1024) {
        int wsel = tile >> 8; tloc = tile & 255; Kd = 512; Nd = 512;
        if (wsel == 0)      { src = Wq; dst = WqkvT; }
        else if (wsel == 1) { src = Wk; dst = WqkvT + (size_t)512 * 512; }
        else if (wsel == 2) { src = Wv; dst = WqkvT + (size_t)1024 * 512; }
        else                { src = Wo; dst = WoT; }
    } else if (tile < 2048) { tloc = tile - 1024; Kd = 512;  Nd = 2048; src = W1; dst = W1T; }
    else                    { tloc = tile - 2048; Kd = 2048; Nd = 512;  src = W2; dst = W2T; }
    int tn = Nd >> 5;
    int k0 = (tloc / tn) << 5, n0 = (tloc % tn) << 5;
    __shared__ float tl[32][33];
    int c = threadIdx.x & 31, r = threadIdx.x >> 5;
    #pragma unroll
    for (int i = 0; i < 4; ++i)
        tl[r + i * 8][c] = src[(size_t)(k0 + r + i * 8) * Nd + n0 + c];
    __syncthreads();
    #pragma unroll
    for (int i = 0; i < 4; ++i)
        dst[(size_t)(n0 + r + i * 8) * Kd + k0 + c] = f2bf(tl[c][r + i * 8]);
}

// ---------------------------------------------------------------------------
// MFMA bf16 GEMM core (round-8): BM=64, BN=128, BK=128, XOR-swizzled LDS.
// ---------------------------------------------------------------------------
template <int MODE>  // 0 = fp32+bias; 1 = bf16+bias+ReLU; 2 = fp32 raw split-K partial
__global__ __launch_bounds__(256) void gemm_std_k(
    const ushort_t* __restrict__ A, const ushort_t* __restrict__ BT,
    const float* __restrict__ bias, void* __restrict__ Cv,
    int N, int K, int Klen, size_t zstride)
{
    __shared__ ushort_t As[64 * 128];    // 16 KB
    __shared__ ushort_t Bs[128 * 128];   // 32 KB

    const int t = threadIdx.x;
    const int w = t >> 6, lane = t & 63, l16 = lane & 15, quad = lane >> 4;
    const int m0 = blockIdx.y * 64;
    const int n0 = blockIdx.x * 128;
    const int kbase = blockIdx.z * Klen;
    const int mbase = (w >> 1) * 32;
    const int nbase = (w & 1) * 64;
    const int lrow = lane >> 4;
    const int lchunk = lane & 15;

    float4v acc[2][4];
    #pragma unroll
    for (int mt = 0; mt < 2; ++mt)
        #pragma unroll
        for (int nt = 0; nt < 4; ++nt)
            acc[mt][nt] = (float4v){0.f, 0.f, 0.f, 0.f};

    for (int ks = kbase; ks < kbase + Klen; ks += 128) {
        __syncthreads();
        for (int c = w; c < 16; c += 4) {
            int rl = c * 4 + lrow;
            gload16(A + (size_t)(m0 + rl) * K + ks + ((lchunk ^ (rl & 7)) << 3),
                    &As[c * 512]);
        }
        for (int c = w; c < 32; c += 4) {
            int rl = c * 4 + lrow;
            gload16(BT + (size_t)(n0 + rl) * K + ks + ((lchunk ^ (rl & 7)) << 3),
                    &Bs[c * 512]);
        }
        __syncthreads();

        #pragma unroll
        for (int co = 0; co < 4; ++co) {
            const int poff = (((co * 4 + quad) ^ (l16 & 7)) << 3);
            short8 af[2], bf8[4];
            #pragma unroll
            for (int mt = 0; mt < 2; ++mt)
                af[mt] = *(const short8*)&As[(mbase + mt * 16 + l16) * 128 + poff];
            #pragma unroll
            for (int nt = 0; nt < 4; ++nt)
                bf8[nt] = *(const short8*)&Bs[(nbase + nt * 16 + l16) * 128 + poff];
            #pragma unroll
            for (int mt = 0; mt < 2; ++mt)
                #pragma unroll
                for (int nt = 0; nt < 4; ++nt)
                    acc[mt][nt] = __builtin_amdgcn_mfma_f32_16x16x32_bf16(
                        af[mt], bf8[nt], acc[mt][nt], 0, 0, 0);
        }
    }

    float* Cf = (float*)Cv + blockIdx.z * zstride;
    #pragma unroll
    for (int mt = 0; mt < 2; ++mt) {
        #pragma unroll
        for (int nt = 0; nt < 4; ++nt) {
            int gcol = n0 + nbase + nt * 16 + l16;
            float b = (MODE == 2) ? 0.f : bias[gcol];
            #pragma unroll
            for (int r = 0; r < 4; ++r) {
                int grow = m0 + mbase + mt * 16 + quad * 4 + r;
                float v = acc[mt][nt][r] + b;
                if (MODE == 1) v = fmaxf(v, 0.f);
                if (MODE == 1) ((ushort_t*)Cv)[(size_t)grow * N + gcol] = f2bf(v);
                else           Cf[(size_t)grow * N + gcol] = v;
            }
        }
    }
}

// ---------------------------------------------------------------------------
// Fused QKV GEMM (round-8 core). Q scale folds 1/sqrt(64) and log2(e).
// ---------------------------------------------------------------------------
__global__ __launch_bounds__(256) void gemm_qkv_k(
    const ushort_t* __restrict__ A, const ushort_t* __restrict__ BT,
    const float* __restrict__ bq, const float* __restrict__ bk,
    const float* __restrict__ bv,
    ushort_t* __restrict__ Qb, ushort_t* __restrict__ Kb,
    ushort_t* __restrict__ VTb)
{
    __shared__ ushort_t As[64 * 128];
    __shared__ ushort_t Bs[128 * 128];

    const int t = threadIdx.x;
    const int w = t >> 6, lane = t & 63, l16 = lane & 15, quad = lane >> 4;
    const int m0 = blockIdx.y * 64;
    const int n0 = blockIdx.x * 128;
    const int mbase = (w >> 1) * 32;
    const int nbase = (w & 1) * 64;
    const int lrow = lane >> 4;
    const int lchunk = lane & 15;
    const int K = 512;

    float4v acc[2][4];
    #pragma unroll
    for (int mt = 0; mt < 2; ++mt)
        #pragma unroll
        for (int nt = 0; nt < 4; ++nt)
            acc[mt][nt] = (float4v){0.f, 0.f, 0.f, 0.f};

    for (int ks = 0; ks < 512; ks += 128) {
        __syncthreads();
        for (int c = w; c < 16; c += 4) {
            int rl = c * 4 + lrow;
            gload16(A + (size_t)(m0 + rl) * K + ks + ((lchunk ^ (rl & 7)) << 3),
                    &As[c * 512]);
        }
        for (int c = w; c < 32; c += 4) {
            int rl = c * 4 + lrow;
            gload16(BT + (size_t)(n0 + rl) * K + ks + ((lchunk ^ (rl & 7)) << 3),
                    &Bs[c * 512]);
        }
        __syncthreads();

        #pragma unroll
        for (int co = 0; co < 4; ++co) {
            const int poff = (((co * 4 + quad) ^ (l16 & 7)) << 3);
            short8 af[2], bf8[4];
            #pragma unroll
            for (int mt = 0; mt < 2; ++mt)
                af[mt] = *(const short8*)&As[(mbase + mt * 16 + l16) * 128 + poff];
            #pragma unroll
            for (int nt = 0; nt < 4; ++nt)
                bf8[nt] = *(const short8*)&Bs[(nbase + nt * 16 + l16) * 128 + poff];
            #pragma unroll
            for (int mt = 0; mt < 2; ++mt)
                #pragma unroll
                for (int nt = 0; nt < 4; ++nt)
                    acc[mt][nt] = __builtin_amdgcn_mfma_f32_16x16x32_bf16(
                        af[mt], bf8[nt], acc[mt][nt], 0, 0, 0);
        }
    }

    const int tsel = n0 >> 9;                       // 0=Q 1=K 2=V (block-uniform)
    const float* bias = (tsel == 0) ? bq : (tsel == 1) ? bk : bv;
    const float scl = (tsel == 0) ? 0.18033688f : 1.0f;  // 0.125 * log2(e)
    ushort_t* dst = (tsel == 0) ? Qb : Kb;

    #pragma unroll
    for (int mt = 0; mt < 2; ++mt) {
        #pragma unroll
        for (int nt = 0; nt < 4; ++nt) {
            int gcol = n0 + nbase + nt * 16 + l16;
            int lcol = gcol - (tsel << 9);
            int h = lcol >> 6, dh = lcol & 63;
            float b = bias[lcol];
            #pragma unroll
            for (int r = 0; r < 4; ++r) {
                int grow = m0 + mbase + mt * 16 + quad * 4 + r;
                int bb = grow >> 11, s = grow & 2047;
                float v = (acc[mt][nt][r] + b) * scl;
                if (tsel < 2)
                    dst[(((size_t)(bb * N_HEADS + h)) * SEQ + s) * HEAD_DIM + dh] = f2bf(v);
                else
                    VTb[(((size_t)(bb * N_HEADS + h)) * HEAD_DIM + dh) * SEQ + s] = f2bf(v);
            }
        }
    }
}

// ---------------------------------------------------------------------------
// bf16 MFMA flash attention v5: r8 v4 structure (async double-buffered K/V via
// global_load_lds, XOR-swizzle, raw s_barrier, vmcnt(4)) + split softmax/PV:
// QK nt-major, then exp2+Ps for keys 0..31, wait, PV c=0 overlapping exp2 for
// keys 32..63, Ps, wait, PV c=1. Fixed-max exp2 softmax, split-K x2.
// ---------------------------------------------------------------------------
__global__ __launch_bounds__(256) void attn_mfma_k(
    const ushort_t* __restrict__ Qg, const ushort_t* __restrict__ Kg,
    const ushort_t* __restrict__ VTg,
    float* __restrict__ Opart, float* __restrict__ Lpart)
{
    __shared__ __align__(16) ushort_t Kbuf[2][64 * 64];   // 8 KB each
    __shared__ __align__(16) ushort_t Vbuf[2][64 * 64];
    __shared__ __align__(16) ushort_t Ps[4][16 * 64];     // swizzled, per-wave

    const int bh = blockIdx.x;
    const int q0 = blockIdx.y * 64;
    const int ks = blockIdx.z;
    const int t = threadIdx.x;
    const int w = t >> 6;
    const int lane = t & 63;
    const int l16 = lane & 15;
    const int quad = lane >> 4;
    const int qbase = q0 + w * 16;
    const float M2 = 14.4269504f;   // 10*log2(e); scores pre-scaled by log2(e)/8

    const int r0 = t >> 3;
    const int r1 = r0 + 32;
    const int g0 = (t & 7) ^ (r0 & 7);
    const int g1 = (t & 7) ^ (r1 & 7);
    const size_t kgrow = (size_t)bh * SEQ;
    const size_t vgrow = (size_t)bh * HEAD_DIM;

#define ATTN_STAGE(b, kb)                                                                  \
    {                                                                                      \
        gload16(Kg + (kgrow + (kb) + r0) * HEAD_DIM + g0 * 8, &Kbuf[b][w * 512]);          \
        gload16(Kg + (kgrow + (kb) + r1) * HEAD_DIM + g1 * 8, &Kbuf[b][2048 + w * 512]);   \
        gload16(VTg + (vgrow + r0) * SEQ + (kb) + g0 * 8, &Vbuf[b][w * 512]);              \
        gload16(VTg + (vgrow + r1) * SEQ + (kb) + g1 * 8, &Vbuf[b][2048 + w * 512]);       \
    }

    short8 aq[2];
    {
        const ushort_t* qp = Qg + ((size_t)bh * SEQ + qbase + l16) * HEAD_DIM + quad * 8;
        aq[0] = *(const short8*)(qp);
        aq[1] = *(const short8*)(qp + 32);
    }

    float4v o[4] = {};
    float l_acc[4] = {0.f, 0.f, 0.f, 0.f};

    ATTN_STAGE(0, ks * 1024)

    for (int kt = 0; kt < 16; ++kt) {
        const int cur = kt & 1;
        if (kt < 15) {
            ATTN_STAGE(cur ^ 1, ks * 1024 + (kt + 1) * 64)
            asm volatile("s_waitcnt vmcnt(4)" ::: "memory");  // tile kt landed (mine)
        } else {
            asm volatile("s_waitcnt vmcnt(0)" ::: "memory");
        }
        asm volatile("s_barrier" ::: "memory");               // tile kt landed (all)

        const ushort_t* Kc = Kbuf[cur];
        const ushort_t* Vc = Vbuf[cur];

        // QK, nt-major: s[nt] complete after its 2 chained MFMAs
        float4v s[4];
        #pragma unroll
        for (int nt = 0; nt < 4; ++nt) {
            s[nt] = (float4v){0.f, 0.f, 0.f, 0.f};
            #pragma unroll
            for (int c = 0; c < 2; ++c) {
                const int poff = (((c * 4 + quad) ^ (l16 & 7)) << 3);
                short8 bk8 = *(const short8*)&Kc[(nt * 16 + l16) * 64 + poff];
                s[nt] = __builtin_amdgcn_mfma_f32_16x16x32_bf16(aq[c], bk8, s[nt], 0, 0, 0);
            }
        }

        // half 1: softmax + Ps for keys 0..31 (nt 0,1)
        #pragma unroll
        for (int nt = 0; nt < 2; ++nt)
            #pragma unroll
            for (int r = 0; r < 4; ++r) {
                float p = exp2f(s[nt][r] - M2);
                l_acc[r] += p;
                int row = quad * 4 + r;
                int key = nt * 16 + l16;
                Ps[w][row * 64 + (((key >> 3) ^ (row & 7)) << 3) + (key & 7)] =
                    f2bf_trunc(p);
            }
        asm volatile("s_waitcnt lgkmcnt(0)" ::: "memory");    // wave-private Ps half 1
        short8 ap0 = *(const short8*)&Ps[w][l16 * 64 + ((quad ^ (l16 & 7)) << 3)];

        // half 2 softmax (independent of PV c=0 -> co-scheduled by compiler)
        float p2[2][4];
        #pragma unroll
        for (int nt = 0; nt < 2; ++nt)
            #pragma unroll
            for (int r = 0; r < 4; ++r) {
                float p = exp2f(s[nt + 2][r] - M2);
                p2[nt][r] = p;
                l_acc[r] += p;
            }

        // PV c=0 (keys 0..31)
        {
            const int poff = ((quad ^ (l16 & 7)) << 3);
            #pragma unroll
            for (int dt = 0; dt < 4; ++dt) {
                short8 bv8 = *(const short8*)&Vc[(dt * 16 + l16) * 64 + poff];
                o[dt] = __builtin_amdgcn_mfma_f32_16x16x32_bf16(ap0, bv8, o[dt], 0, 0, 0);
            }
        }

        // Ps half 2 (keys 32..63)
        #pragma unroll
        for (int nt = 0; nt < 2; ++nt)
            #pragma unroll
            for (int r = 0; r < 4; ++r) {
                int row = quad * 4 + r;
                int key = (nt + 2) * 16 + l16;
                Ps[w][row * 64 + (((key >> 3) ^ (row & 7)) << 3) + (key & 7)] =
                    f2bf_trunc(p2[nt][r]);
            }
        asm volatile("s_waitcnt lgkmcnt(0)" ::: "memory");    // wave-private Ps half 2

        // PV c=1 (keys 32..63)
        {
            short8 ap1 = *(const short8*)&Ps[w][l16 * 64 + (((4 + quad) ^ (l16 & 7)) << 3)];
            const int poff = ((((4) + quad) ^ (l16 & 7)) << 3);
            #pragma unroll
            for (int dt = 0; dt < 4; ++dt) {
                short8 bv8 = *(const short8*)&Vc[(dt * 16 + l16) * 64 + poff];
                o[dt] = __builtin_amdgcn_mfma_f32_16x16x32_bf16(ap1, bv8, o[dt], 0, 0, 0);
            }
        }

        asm volatile("s_barrier" ::: "memory");   // all waves done reading buf[cur]
    }
#undef ATTN_STAGE

    const size_t pbase = ((size_t)(ks * 16 + bh)) * SEQ;
    #pragma unroll
    for (int r = 0; r < 4; ++r) {
        float L = l_acc[r];
        #pragma unroll
        for (int msk = 1; msk < 16; msk <<= 1) L += __shfl_xor(L, msk);
        int qrow = qbase + quad * 4 + r;
        if (l16 == 0) Lpart[pbase + qrow] = L;
        #pragma unroll
        for (int dt = 0; dt < 4; ++dt)
            Opart[(pbase + qrow) * HEAD_DIM + dt * 16 + l16] = o[dt][r];
    }
}

// ---------------------------------------------------------------------------
// Combine 2 split-K attention partials: ctx = sum(O)/sum(l), bf16 [B,S,D].
// ---------------------------------------------------------------------------
__global__ __launch_bounds__(256) void attn_comb_k(
    const float* __restrict__ Op, const float* __restrict__ Lp,
    ushort_t* __restrict__ ctx)
{
    int g = blockIdx.x * 256 + threadIdx.x;      // 0..524287
    int d4 = g & 15;
    int q  = (g >> 4) & 2047;
    int bh = g >> 15;
    float ax = 0.f, ay = 0.f, az = 0.f, aw = 0.f, L = 0.f;
    #pragma unroll
    for (int ks = 0; ks < 2; ++ks) {
        size_t row = ((size_t)(ks * 16 + bh) * SEQ + q) * HEAD_DIM;
        float4 a = ((const float4*)(Op + row))[d4];
        ax += a.x; ay += a.y; az += a.z; aw += a.w;
        L += Lp[ks * 16 * SEQ + bh * SEQ + q];
    }
    float inv = 1.0f / L;
    ushort4 o4;
    o4.x = f2bf(ax * inv);
    o4.y = f2bf(ay * inv);
    o4.z = f2bf(az * inv);
    o4.w = f2bf(aw * inv);
    int bb = bh >> 3, hh = bh & 7;
    *(ushort4*)&ctx[((size_t)(bb * SEQ + q)) * D_MODEL + hh * HEAD_DIM + d4 * 4] = o4;
}

// ---------------------------------------------------------------------------
// Residual + LayerNorm over split-K partials:
// O[row] = LN(X + P0 + P1 + bias) * gamma + beta; optional bf16 copy.
// ---------------------------------------------------------------------------
template <int WRITE_BF>
__global__ __launch_bounds__(256) void add_ln_k(
    const float* __restrict__ X, const float* __restrict__ P0,
    const float* __restrict__ P1, const float* __restrict__ bias,
    const float* __restrict__ gam, const float* __restrict__ bet,
    float* __restrict__ O, ushort_t* __restrict__ Ob)
{
    const int row = blockIdx.x;
    const int t = threadIdx.x;
    const size_t ro = (size_t)row * D_MODEL;

    float v0 = X[ro + t]       + P0[ro + t]       + P1[ro + t]       + bias[t];
    float v1 = X[ro + t + 256] + P0[ro + t + 256] + P1[ro + t + 256] + bias[t + 256];
    float s = v0 + v1;
    float ss = v0 * v0 + v1 * v1;
    #pragma unroll
    for (int off = 32; off > 0; off >>= 1) {
        s  += __shfl_down(s, off);
        ss += __shfl_down(ss, off);
    }
    __shared__ float sb[4], ssb[4];
    if ((t & 63) == 0) { sb[t >> 6] = s; ssb[t >> 6] = ss; }
    __syncthreads();
    float S  = sb[0] + sb[1] + sb[2] + sb[3];
    float SS = ssb[0] + ssb[1] + ssb[2] + ssb[3];
    float mu  = S * (1.0f / D_MODEL);
    float var = SS * (1.0f / D_MODEL) - mu * mu;
    float inv = rsqrtf(var + 1e-5f);
    float o0 = (v0 - mu) * inv * gam[t] + bet[t];
    float o1 = (v1 - mu) * inv * gam[t + 256] + bet[t + 256];
    O[ro + t]       = o0;
    O[ro + t + 256] = o1;
    if (WRITE_BF) {
        Ob[ro + t]       = f2bf(o0);
        Ob[ro + t + 256] = f2bf(o1);
    }
}

// ---------------------------------------------------------------------------
extern "C" void kernel_launch(void* const* d_in, const int* in_sizes, int n_in,
                              void* d_out, int out_size, void* d_ws, size_t ws_size,
                              hipStream_t stream)
{
    const float* x   = (const float*)d_in[0];
    const float* Wq  = (const float*)d_in[1];
    const float* bq  = (const float*)d_in[2];
    const float* Wk  = (const float*)d_in[3];
    const float* bk  = (const float*)d_in[4];
    const float* Wv  = (const float*)d_in[5];
    const float* bv  = (const float*)d_in[6];
    const float* Wo  = (const float*)d_in[7];
    const float* bo  = (const float*)d_in[8];
    const float* W1  = (const float*)d_in[9];
    const float* b1  = (const float*)d_in[10];
    const float* W2  = (const float*)d_in[11];
    const float* b2  = (const float*)d_in[12];
    const float* g1  = (const float*)d_in[13];
    const float* be1 = (const float*)d_in[14];
    const float* g2  = (const float*)d_in[15];
    const float* be2 = (const float*)d_in[16];
    float* out = (float*)d_out;
    float* ws  = (float*)d_ws;

    // float-unit offsets; max end 13,172,736 fl = 52.7 MB (lifetime-overlaid)
    ushort_t* WoT   = (ushort_t*)(ws);               // [512][512] bf16
    ushort_t* W1T   = (ushort_t*)(ws + 131072);      // [2048][512]
    ushort_t* W2T   = (ushort_t*)(ws + 655360);      // [512][2048]
    ushort_t* WqkvT = (ushort_t*)(ws + 1179648);     // [1536][512]
    ushort_t* xb    = (ushort_t*)(ws + 1572864);     // [4096][512] bf16
    ushort_t* Qb    = (ushort_t*)(ws + 2621440);     // [16][2048][64]
    ushort_t* Kb    = (ushort_t*)(ws + 3670016);
    ushort_t* VTb   = (ushort_t*)(ws + 4718592);     // [16][64][2048]
    ushort_t* Ctx   = (ushort_t*)(ws + 5767168);     // [4096][512] bf16
    float*    Lpart = ws + 6815744;                  // [2][16][2048]
    float*    Hh    = ws + 6881280;                  // [4096][512] fp32
    float*    P0    = ws + 8978432;                  // [4096][512] fp32 partial
    float*    P1    = ws + 11075584;                 // [4096][512] fp32 partial
    float*    Opart = ws + 8978432;                  // [2][16][2048][64] (P0+P1 slot)
    ushort_t* FF1   = (ushort_t*)(ws + 1572864);     // [4096][2048] bf16 (xb/Qb slot)
    ushort_t* Hhb   = (ushort_t*)(ws + 5767168);     // [4096][512] bf16 (Ctx slot)

    // conversions (fused)
    prep_k<<<5120, 256, 0, stream>>>(x, Wq, Wk, Wv, Wo, W1, W2, xb, WqkvT, WoT, W1T, W2T);

    // QKV projection: BM=64, BK=128 swizzled core; 768 blocks
    gemm_qkv_k<<<dim3(12, 64), 256, 0, stream>>>(xb, WqkvT, bq, bk, bv, Qb, Kb, VTb);

    // flash attention v5 (async pipelined + split softmax/PV), split-K x2
    attn_mfma_k<<<dim3(16, 32, 2), 256, 0, stream>>>(Qb, Kb, VTb, Opart, Lpart);
    attn_comb_k<<<2048, 256, 0, stream>>>(Opart, Lpart, Ctx);

    // output projection: split-K x2, raw fp32 partials (bias folded into LN1)
    gemm_std_k<2><<<dim3(4, 64, 2), 256, 0, stream>>>(
        Ctx, WoT, nullptr, P0, 512, 512, 256, (size_t)MROWS * D_MODEL);

    // h = LN(x + p0 + p1 + bo)
    add_ln_k<1><<<4096, 256, 0, stream>>>(x, P0, P1, bo, g1, be1, Hh, Hhb);

    // FFN up: bf16 + bias + ReLU; 1024 blocks
    gemm_std_k<1><<<dim3(16, 64), 256, 0, stream>>>(
        Hhb, W1T, b1, FF1, 2048, 512, 512, 0);

    // FFN down: split-K x2, raw fp32 partials (bias folded into LN2)
    gemm_std_k<2><<<dim3(4, 64, 2), 256, 0, stream>>>(
        FF1, W2T, nullptr, P0, 512, 2048, 1024, (size_t)MROWS * D_MODEL);

    // out = LN(h + q0 + q1 + b2)
    add_ln_k<0><<<4096, 256, 0, stream>>>(Hh, P0, P1, b2, g2, be2, out, (ushort_t*)nullptr);
}